// Round 1
// baseline (1579.596 us; speedup 1.0000x reference)
//
#include <hip/hip_runtime.h>
#include <math.h>

// Problem constants (B,C,H,W fixed by the reference)
#define NB 4
#define NC 96
#define NH 128
#define NW 128
#define HWSZ (NH * NW)          // 16384
#define NK 9                    // 3x3 kernel positions
#define AUXC 27                 // 18 offset + 9 mask channels
#define CKK (NC * NK)           // 864

// ---------------------------------------------------------------------------
// Kernel 1: 3x3 conv producing 18 offset channels + 9 mask channels (with
// 2*sigmoid applied). One thread per output pixel, 27 accumulators.
// Weight indices are wave-uniform -> compiler emits scalar loads.
// ---------------------------------------------------------------------------
__global__ __launch_bounds__(256) void conv27_kernel(
    const float* __restrict__ in,
    const float* __restrict__ offw, const float* __restrict__ offb,
    const float* __restrict__ modw, const float* __restrict__ modb,
    float* __restrict__ aux)
{
    int p = blockIdx.x * 256 + threadIdx.x;    // 0 .. NB*HWSZ-1
    int b = p >> 14;
    int rem = p & (HWSZ - 1);
    int y = rem >> 7;
    int x = rem & (NW - 1);

    float acc[AUXC];
#pragma unroll
    for (int oc = 0; oc < 18; ++oc) acc[oc] = offb[oc];
#pragma unroll
    for (int oc = 0; oc < 9; ++oc) acc[18 + oc] = modb[oc];

    const float* xin = in + b * (NC * HWSZ);
#pragma unroll 2
    for (int c = 0; c < NC; ++c) {
        const float* xc = xin + c * HWSZ;
#pragma unroll
        for (int ky = 0; ky < 3; ++ky) {
            int yy = y + ky - 1;
            bool vy = (yy >= 0) && (yy < NH);
#pragma unroll
            for (int kx = 0; kx < 3; ++kx) {
                int xx = x + kx - 1;
                bool v = vy && (xx >= 0) && (xx < NW);
                float xv = v ? xc[yy * NW + xx] : 0.f;
                int wbase = c * NK + ky * 3 + kx;
#pragma unroll
                for (int oc = 0; oc < 18; ++oc)
                    acc[oc] = fmaf(xv, offw[oc * CKK + wbase], acc[oc]);
#pragma unroll
                for (int oc = 0; oc < 9; ++oc)
                    acc[18 + oc] = fmaf(xv, modw[oc * CKK + wbase], acc[18 + oc]);
            }
        }
    }

    float* ap = aux + b * (AUXC * HWSZ) + rem;
#pragma unroll
    for (int oc = 0; oc < 18; ++oc) ap[oc * HWSZ] = acc[oc];
#pragma unroll
    for (int oc = 0; oc < 9; ++oc) {
        float z = acc[18 + oc];
        ap[(18 + oc) * HWSZ] = 2.f / (1.f + __expf(-z));
    }
}

// ---------------------------------------------------------------------------
// Kernel 2: deformable sampling + channel contraction.
// Block = 64 consecutive pixels (half a row), 256 threads (4 waves).
// Phase 1: per (pixel,k) geometry -> 4 clamped addresses + 4 mask-folded
//          bilinear weights in LDS (576 entries).
// Phase 2: per input channel c: all threads produce S[k][px] (sampled values)
//          into LDS, then each wave accumulates 24 output channels
//          (weight rows are wave-uniform -> scalar loads).
// ---------------------------------------------------------------------------
__global__ __launch_bounds__(256) void deform_kernel(
    const float* __restrict__ in,    // (B,C,H,W)
    const float* __restrict__ aux,   // (B,27,H,W)
    const float* __restrict__ wmat,  // (96,96,3,3) == [oc][c][k]
    float* __restrict__ out)         // (B,C,H,W) pre-BN
{
    __shared__ int   sAddr[4][576];
    __shared__ float sWgt[4][576];
    __shared__ float sS[576];        // [k][px] flat: e = k*64+px

    int t = threadIdx.x;
    int base = blockIdx.x * 64;      // pixel base
    int b = base >> 14;
    int rem0 = base & (HWSZ - 1);
    int y = rem0 >> 7;
    int x0 = rem0 & (NW - 1);        // 0 or 64

    const float* auxb = aux + b * (AUXC * HWSZ);

    // ---- phase 1: geometry ----
    for (int e = t; e < 576; e += 256) {
        int px = e & 63;
        int k  = e >> 6;
        int xcol = x0 + px;
        int idx = y * NW + xcol;
        float offy = auxb[(2 * k) * HWSZ + idx];
        float offx = auxb[(2 * k + 1) * HWSZ + idx];
        float m    = auxb[(18 + k) * HWSZ + idx];
        int ky = k / 3, kx = k - 3 * (k / 3);
        float py  = (float)(y - 1 + ky) + offy;
        float pxf = (float)(xcol - 1 + kx) + offx;
        float y0f = floorf(py), x0f = floorf(pxf);
        float dy = py - y0f, dx = pxf - x0f;
        int iy0 = (int)y0f, ix0 = (int)x0f;
        int iy1 = iy0 + 1,  ix1 = ix0 + 1;

        bool vy0 = (iy0 >= 0) && (iy0 < NH);
        bool vy1 = (iy1 >= 0) && (iy1 < NH);
        bool vx0 = (ix0 >= 0) && (ix0 < NW);
        bool vx1 = (ix1 >= 0) && (ix1 < NW);
        int cy0 = min(max(iy0, 0), NH - 1);
        int cy1 = min(max(iy1, 0), NH - 1);
        int cx0 = min(max(ix0, 0), NW - 1);
        int cx1 = min(max(ix1, 0), NW - 1);

        float w00 = (1.f - dy) * (1.f - dx) * m; if (!(vy0 && vx0)) w00 = 0.f;
        float w01 = (1.f - dy) * dx * m;         if (!(vy0 && vx1)) w01 = 0.f;
        float w10 = dy * (1.f - dx) * m;         if (!(vy1 && vx0)) w10 = 0.f;
        float w11 = dy * dx * m;                 if (!(vy1 && vx1)) w11 = 0.f;

        sAddr[0][e] = cy0 * NW + cx0;  sWgt[0][e] = w00;
        sAddr[1][e] = cy0 * NW + cx1;  sWgt[1][e] = w01;
        sAddr[2][e] = cy1 * NW + cx0;  sWgt[2][e] = w10;
        sAddr[3][e] = cy1 * NW + cx1;  sWgt[3][e] = w11;
    }
    __syncthreads();

    // ---- phase 2: per-channel produce + consume ----
    float acc[24];
#pragma unroll
    for (int i = 0; i < 24; ++i) acc[i] = 0.f;

    int og = __builtin_amdgcn_readfirstlane(t >> 6);   // wave id, uniform
    int px = t & 63;
    const float* xb = in + b * (NC * HWSZ);

    for (int c = 0; c < NC; ++c) {
        const float* xc = xb + c * HWSZ;
        // produce S (576 entries across 256 threads)
#pragma unroll
        for (int r = 0; r < 3; ++r) {
            int e = t + r * 256;
            if (r < 2 || t < 64) {
                float v = sWgt[0][e] * xc[sAddr[0][e]]
                        + sWgt[1][e] * xc[sAddr[1][e]]
                        + sWgt[2][e] * xc[sAddr[2][e]]
                        + sWgt[3][e] * xc[sAddr[3][e]];
                sS[e] = v;
            }
        }
        __syncthreads();

        // consume: 24 output channels per wave
        float s[NK];
#pragma unroll
        for (int k = 0; k < NK; ++k) s[k] = sS[k * 64 + px];
        const float* wr = wmat + (og * 24) * CKK + c * NK;
#pragma unroll
        for (int i = 0; i < 24; ++i) {
            const float* wv = wr + i * CKK;
#pragma unroll
            for (int k = 0; k < NK; ++k)
                acc[i] = fmaf(s[k], wv[k], acc[i]);
        }
        __syncthreads();
    }

    int rem = y * NW + x0 + px;
    float* op = out + (b * NC + og * 24) * HWSZ + rem;
#pragma unroll
    for (int i = 0; i < 24; ++i) op[i * HWSZ] = acc[i];
}

// ---------------------------------------------------------------------------
// Kernel 3: BN statistics. One block per channel, deterministic (no atomics).
// Emits scale[c] = gamma*rsqrt(var+eps), shift[c] = beta - mean*scale.
// ---------------------------------------------------------------------------
__global__ __launch_bounds__(256) void bnstats_kernel(
    const float* __restrict__ h, const float* __restrict__ g,
    const float* __restrict__ bt, float* __restrict__ sc)
{
    int c = blockIdx.x;
    float s = 0.f, s2 = 0.f;
    for (int b = 0; b < NB; ++b) {
        const float4* p = (const float4*)(h + (size_t)(b * NC + c) * HWSZ);
        for (int i = threadIdx.x; i < HWSZ / 4; i += 256) {
            float4 v = p[i];
            s  += v.x + v.y + v.z + v.w;
            s2 += v.x * v.x + v.y * v.y + v.z * v.z + v.w * v.w;
        }
    }
#pragma unroll
    for (int o = 32; o > 0; o >>= 1) {
        s  += __shfl_down(s, o);
        s2 += __shfl_down(s2, o);
    }
    __shared__ float red[8];
    int wv = threadIdx.x >> 6, ln = threadIdx.x & 63;
    if (ln == 0) { red[wv] = s; red[4 + wv] = s2; }
    __syncthreads();
    if (threadIdx.x == 0) {
        float ts  = red[0] + red[1] + red[2] + red[3];
        float ts2 = red[4] + red[5] + red[6] + red[7];
        const float inv_n = 1.f / (float)(NB * HWSZ);
        float mean = ts * inv_n;
        float var  = ts2 * inv_n - mean * mean;
        float scale = g[c] * rsqrtf(var + 1e-5f);
        sc[c] = scale;
        sc[NC + c] = bt[c] - mean * scale;
    }
}

// ---------------------------------------------------------------------------
// Kernel 4: apply BN + leaky ReLU in place (layer 1 output)
// ---------------------------------------------------------------------------
__global__ __launch_bounds__(256) void bnlrelu_kernel(
    float* __restrict__ h, const float* __restrict__ sc)
{
    const int n4 = NB * NC * HWSZ / 4;
    for (int i = blockIdx.x * 256 + threadIdx.x; i < n4; i += gridDim.x * 256) {
        int c = (i >> 12) % NC;      // i/(HWSZ/4) % NC
        float scale = sc[c], shift = sc[NC + c];
        float4 v = ((const float4*)h)[i];
        float4 o;
        o.x = fmaf(scale, v.x, shift); o.x = o.x >= 0.f ? o.x : 0.1f * o.x;
        o.y = fmaf(scale, v.y, shift); o.y = o.y >= 0.f ? o.y : 0.1f * o.y;
        o.z = fmaf(scale, v.z, shift); o.z = o.z >= 0.f ? o.z : 0.1f * o.z;
        o.w = fmaf(scale, v.w, shift); o.w = o.w >= 0.f ? o.w : 0.1f * o.w;
        ((float4*)h)[i] = o;
    }
}

// ---------------------------------------------------------------------------
// Kernel 5: final  out = x + BN(h2_raw)   (h2_raw lives in d_out, in place)
// ---------------------------------------------------------------------------
__global__ __launch_bounds__(256) void final_kernel(
    float* __restrict__ out, const float* __restrict__ x,
    const float* __restrict__ sc)
{
    const int n4 = NB * NC * HWSZ / 4;
    for (int i = blockIdx.x * 256 + threadIdx.x; i < n4; i += gridDim.x * 256) {
        int c = (i >> 12) % NC;
        float scale = sc[c], shift = sc[NC + c];
        float4 v = ((const float4*)out)[i];
        float4 xv = ((const float4*)x)[i];
        float4 o;
        o.x = xv.x + fmaf(scale, v.x, shift);
        o.y = xv.y + fmaf(scale, v.y, shift);
        o.z = xv.z + fmaf(scale, v.z, shift);
        o.w = xv.w + fmaf(scale, v.w, shift);
        ((float4*)out)[i] = o;
    }
}

// ---------------------------------------------------------------------------
extern "C" void kernel_launch(void* const* d_in, const int* in_sizes, int n_in,
                              void* d_out, int out_size, void* d_ws, size_t ws_size,
                              hipStream_t stream)
{
    const float* x        = (const float*)d_in[0];
    const float* d1_off_w = (const float*)d_in[1];
    const float* d1_off_b = (const float*)d_in[2];
    const float* d1_mod_w = (const float*)d_in[3];
    const float* d1_mod_b = (const float*)d_in[4];
    const float* d1_w     = (const float*)d_in[5];
    const float* d2_off_w = (const float*)d_in[6];
    const float* d2_off_b = (const float*)d_in[7];
    const float* d2_mod_w = (const float*)d_in[8];
    const float* d2_mod_b = (const float*)d_in[9];
    const float* d2_w     = (const float*)d_in[10];
    const float* bn_g     = (const float*)d_in[11];
    const float* bn_b     = (const float*)d_in[12];
    float* out = (float*)d_out;

    // workspace layout (floats): h1 (6291456) | aux (1769472) | sc (192)
    float* h1  = (float*)d_ws;
    float* aux = h1 + (size_t)NB * NC * HWSZ;
    float* sc  = aux + (size_t)NB * AUXC * HWSZ;

    const int npix = NB * HWSZ;              // 65536

    // ---- layer 1 ----
    conv27_kernel<<<npix / 256, 256, 0, stream>>>(x, d1_off_w, d1_off_b,
                                                  d1_mod_w, d1_mod_b, aux);
    deform_kernel<<<npix / 64, 256, 0, stream>>>(x, aux, d1_w, h1);
    bnstats_kernel<<<NC, 256, 0, stream>>>(h1, bn_g, bn_b, sc);
    bnlrelu_kernel<<<2048, 256, 0, stream>>>(h1, sc);

    // ---- layer 2 ----
    conv27_kernel<<<npix / 256, 256, 0, stream>>>(h1, d2_off_w, d2_off_b,
                                                  d2_mod_w, d2_mod_b, aux);
    deform_kernel<<<npix / 64, 256, 0, stream>>>(h1, aux, d2_w, out);
    bnstats_kernel<<<NC, 256, 0, stream>>>(out, bn_g, bn_b, sc);
    final_kernel<<<2048, 256, 0, stream>>>(out, x, sc);
}

// Round 2
// 1390.779 us; speedup vs baseline: 1.1358x; 1.1358x over previous
//
#include <hip/hip_runtime.h>
#include <math.h>

#define NB 4
#define NC 96
#define NH 128
#define NW 128
#define HWSZ (NH * NW)          // 16384
#define NK 9
#define AUXC 27                 // 18 offset + 9 mask channels
#define CKK (NC * NK)           // 864
#define WT_STRIDE 28            // 27 outputs + 1 pad (16B-aligned rows)
#define WT_ELEMS (CKK * WT_STRIDE)      // 24192
#define WD_ELEMS (CKK * NC)             // 82944

// ---------------------------------------------------------------------------
// Kernel 0: weight transposes for this layer.
//   wT[(c*9+tap)*28 + oc] = (oc<18 ? offw[oc][c][tap] : modw[oc-18][c][tap])
//   wd[(c*9+k)*96 + oc]   = w[oc][c][k]
// ---------------------------------------------------------------------------
__global__ __launch_bounds__(256) void prep_weights_kernel(
    const float* __restrict__ offw, const float* __restrict__ modw,
    const float* __restrict__ w,
    float* __restrict__ wT, float* __restrict__ wd)
{
    int idx = blockIdx.x * 256 + threadIdx.x;
    if (idx < WT_ELEMS) {
        int row = idx / WT_STRIDE;          // c*9+tap
        int col = idx - row * WT_STRIDE;    // oc
        float v = 0.f;
        if (col < 18)      v = offw[col * CKK + row];
        else if (col < 27) v = modw[(col - 18) * CKK + row];
        wT[idx] = v;
    }
    int j = idx - WT_ELEMS;
    if (j >= 0 && j < WD_ELEMS) {
        int row = j / NC;                   // c*9+k
        int oc  = j - row * NC;
        wd[j] = w[oc * CKK + row];
    }
}

// ---------------------------------------------------------------------------
// Kernel 1: 3x3 conv -> 18 offset + 9 mask (2*sigmoid applied).
// Block = 512 threads: px = t&127 (one row), g = t>>7 (4 channel groups of 24).
// Grid = NB*NH = 512 blocks. Weights via contiguous s_load rows of wT.
// ---------------------------------------------------------------------------
__global__ __launch_bounds__(512, 4) void conv27_kernel(
    const float* __restrict__ in,
    const float* __restrict__ wT,
    const float* __restrict__ offb, const float* __restrict__ modb,
    float* __restrict__ aux)
{
    __shared__ float red[3][AUXC][NW];      // 41472 B

    int t  = threadIdx.x;
    int px = t & 127;
    int g  = t >> 7;
    int b  = blockIdx.x >> 7;
    int y  = blockIdx.x & 127;

    const bool hasT = (y > 0), hasB = (y < NH - 1);   // uniform
    int pxl = px > 0 ? px - 1 : 0;
    int pxr = px < NW - 1 ? px + 1 : NW - 1;
    bool edgeL = (px == 0), edgeR = (px == NW - 1);

    int c0 = g * 24;
    float acc[AUXC];
#pragma unroll
    for (int i = 0; i < AUXC; ++i) acc[i] = 0.f;

    const float* imgb = in + (size_t)b * NC * HWSZ + y * NW;

    // load 9 taps for channel c into v[]
    auto loadch = [&](int c, float* v) {
        const float* rm = imgb + c * HWSZ;
        // middle row (always valid)
        float l1 = rm[pxl], m1 = rm[px], r1 = rm[pxr];
        float l0 = 0.f, m0 = 0.f, r0 = 0.f;
        float l2 = 0.f, m2 = 0.f, r2 = 0.f;
        if (hasT) { const float* rt = rm - NW; l0 = rt[pxl]; m0 = rt[px]; r0 = rt[pxr]; }
        if (hasB) { const float* rb = rm + NW; l2 = rb[pxl]; m2 = rb[px]; r2 = rb[pxr]; }
        if (edgeL) { l0 = 0.f; l1 = 0.f; l2 = 0.f; }
        if (edgeR) { r0 = 0.f; r1 = 0.f; r2 = 0.f; }
        v[0] = l0; v[1] = m0; v[2] = r0;
        v[3] = l1; v[4] = m1; v[5] = r1;
        v[6] = l2; v[7] = m2; v[8] = r2;
    };

    float v[9];
    loadch(c0, v);
    for (int c = c0; c < c0 + 24; ++c) {
        float nv[9];
        int cn = (c + 1 < c0 + 24) ? c + 1 : c;   // uniform select
        loadch(cn, nv);
        const float* wb = wT + c * NK * WT_STRIDE;
#pragma unroll
        for (int tap = 0; tap < 9; ++tap) {
            const float* wrow = wb + tap * WT_STRIDE;   // uniform -> s_loads
#pragma unroll
            for (int oc = 0; oc < AUXC; ++oc)
                acc[oc] = fmaf(v[tap], wrow[oc], acc[oc]);
        }
#pragma unroll
        for (int i = 0; i < 9; ++i) v[i] = nv[i];
    }

    if (g > 0) {
#pragma unroll
        for (int oc = 0; oc < AUXC; ++oc) red[g - 1][oc][px] = acc[oc];
    }
    __syncthreads();
    if (g == 0) {
        float* ap = aux + (size_t)b * AUXC * HWSZ + y * NW + px;
#pragma unroll
        for (int oc = 0; oc < AUXC; ++oc) {
            float s = acc[oc] + red[0][oc][px] + red[1][oc][px] + red[2][oc][px];
            if (oc < 18) {
                ap[oc * HWSZ] = s + offb[oc];
            } else {
                float z = s + modb[oc - 18];
                ap[oc * HWSZ] = 2.f / (1.f + __expf(-z));
            }
        }
    }
}

// ---------------------------------------------------------------------------
// Kernel 2: deformable sampling + contraction.
// Block = 64 pixels x 4 waves; per wave 24 output channels.
// 2 channels per iteration, double-buffered sS -> 1 barrier / 2 channels.
// Weights via wd (24 contiguous floats per (c,k) per wave -> s_load_dwordx8).
// ---------------------------------------------------------------------------
__global__ __launch_bounds__(256, 4) void deform_kernel(
    const float* __restrict__ in,    // (B,C,H,W)
    const float* __restrict__ aux,   // (B,27,H,W)
    const float* __restrict__ wd,    // [(c*9+k)*96 + oc]
    float* __restrict__ out)         // (B,C,H,W) pre-BN
{
    __shared__ int   sAddr[4][576];
    __shared__ float sWgt[4][576];
    __shared__ float sS[2][2][576];  // [buf][ch01][k*64+px]

    int t = threadIdx.x;
    int base = blockIdx.x * 64;
    int b = base >> 14;
    int rem0 = base & (HWSZ - 1);
    int y = rem0 >> 7;
    int x0 = rem0 & (NW - 1);

    const float* auxb = aux + (size_t)b * AUXC * HWSZ;

    // ---- geometry ----
    for (int e = t; e < 576; e += 256) {
        int px = e & 63;
        int k  = e >> 6;
        int xcol = x0 + px;
        int idx = y * NW + xcol;
        float offy = auxb[(2 * k) * HWSZ + idx];
        float offx = auxb[(2 * k + 1) * HWSZ + idx];
        float m    = auxb[(18 + k) * HWSZ + idx];
        int ky = k / 3, kx = k - 3 * (k / 3);
        float py  = (float)(y - 1 + ky) + offy;
        float pxf = (float)(xcol - 1 + kx) + offx;
        float y0f = floorf(py), x0f = floorf(pxf);
        float dy = py - y0f, dx = pxf - x0f;
        int iy0 = (int)y0f, ix0 = (int)x0f;
        int iy1 = iy0 + 1,  ix1 = ix0 + 1;

        bool vy0 = (iy0 >= 0) && (iy0 < NH);
        bool vy1 = (iy1 >= 0) && (iy1 < NH);
        bool vx0 = (ix0 >= 0) && (ix0 < NW);
        bool vx1 = (ix1 >= 0) && (ix1 < NW);
        int cy0 = min(max(iy0, 0), NH - 1);
        int cy1 = min(max(iy1, 0), NH - 1);
        int cx0 = min(max(ix0, 0), NW - 1);
        int cx1 = min(max(ix1, 0), NW - 1);

        float w00 = (1.f - dy) * (1.f - dx) * m; if (!(vy0 && vx0)) w00 = 0.f;
        float w01 = (1.f - dy) * dx * m;         if (!(vy0 && vx1)) w01 = 0.f;
        float w10 = dy * (1.f - dx) * m;         if (!(vy1 && vx0)) w10 = 0.f;
        float w11 = dy * dx * m;                 if (!(vy1 && vx1)) w11 = 0.f;

        sAddr[0][e] = cy0 * NW + cx0;  sWgt[0][e] = w00;
        sAddr[1][e] = cy0 * NW + cx1;  sWgt[1][e] = w01;
        sAddr[2][e] = cy1 * NW + cx0;  sWgt[2][e] = w10;
        sAddr[3][e] = cy1 * NW + cx1;  sWgt[3][e] = w11;
    }
    __syncthreads();

    float acc[24];
#pragma unroll
    for (int i = 0; i < 24; ++i) acc[i] = 0.f;

    int og = __builtin_amdgcn_readfirstlane(t >> 6);
    int px = t & 63;
    const float* xb = in + (size_t)b * NC * HWSZ;

    auto produce = [&](int c, int buf) {
        const float* xc0 = xb + c * HWSZ;
        const float* xc1 = xc0 + HWSZ;
#pragma unroll
        for (int r = 0; r < 3; ++r) {
            int e = t + r * 256;
            if (r < 2 || t < 64) {
                int   a0 = sAddr[0][e], a1 = sAddr[1][e];
                int   a2 = sAddr[2][e], a3 = sAddr[3][e];
                float w0 = sWgt[0][e], w1 = sWgt[1][e];
                float w2 = sWgt[2][e], w3 = sWgt[3][e];
                sS[buf][0][e] = w0 * xc0[a0] + w1 * xc0[a1]
                              + w2 * xc0[a2] + w3 * xc0[a3];
                sS[buf][1][e] = w0 * xc1[a0] + w1 * xc1[a1]
                              + w2 * xc1[a2] + w3 * xc1[a3];
            }
        }
    };

    produce(0, 0);
    __syncthreads();

    for (int c = 0; c < NC; c += 2) {
        int buf = (c >> 1) & 1;
        if (c + 2 < NC) produce(c + 2, buf ^ 1);

        float s0[NK], s1[NK];
#pragma unroll
        for (int k = 0; k < NK; ++k) {
            s0[k] = sS[buf][0][k * 64 + px];
            s1[k] = sS[buf][1][k * 64 + px];
        }
#pragma unroll
        for (int k = 0; k < NK; ++k) {
            const float* w0 = wd + (c * NK + k) * NC + og * 24;       // uniform
            const float* w1 = wd + ((c + 1) * NK + k) * NC + og * 24; // uniform
#pragma unroll
            for (int i = 0; i < 24; ++i) {
                acc[i] = fmaf(s0[k], w0[i], acc[i]);
                acc[i] = fmaf(s1[k], w1[i], acc[i]);
            }
        }
        __syncthreads();
    }

    int rem = y * NW + x0 + px;
    float* op = out + ((size_t)b * NC + og * 24) * HWSZ + rem;
#pragma unroll
    for (int i = 0; i < 24; ++i) op[i * HWSZ] = acc[i];
}

// ---------------------------------------------------------------------------
// Kernel 3a: per-(b,c) partial sums.  Kernel 3b: finalize scale/shift.
// ---------------------------------------------------------------------------
__global__ __launch_bounds__(256) void bnstats_kernel(
    const float* __restrict__ h, float* __restrict__ part)
{
    int bc = blockIdx.x;                 // 0..383 = b*NC+c
    const float4* p = (const float4*)(h + (size_t)bc * HWSZ);
    float s = 0.f, s2 = 0.f;
    for (int i = threadIdx.x; i < HWSZ / 4; i += 256) {
        float4 v = p[i];
        s  += v.x + v.y + v.z + v.w;
        s2 += v.x * v.x + v.y * v.y + v.z * v.z + v.w * v.w;
    }
#pragma unroll
    for (int o = 32; o > 0; o >>= 1) {
        s  += __shfl_down(s, o);
        s2 += __shfl_down(s2, o);
    }
    __shared__ float red[8];
    int wv = threadIdx.x >> 6, ln = threadIdx.x & 63;
    if (ln == 0) { red[wv] = s; red[4 + wv] = s2; }
    __syncthreads();
    if (threadIdx.x == 0) {
        part[bc]            = red[0] + red[1] + red[2] + red[3];
        part[NB * NC + bc]  = red[4] + red[5] + red[6] + red[7];
    }
}

__global__ __launch_bounds__(128) void bnfinalize_kernel(
    const float* __restrict__ part, const float* __restrict__ g,
    const float* __restrict__ bt, float* __restrict__ sc)
{
    int c = threadIdx.x;
    if (c >= NC) return;
    float s = 0.f, s2 = 0.f;
#pragma unroll
    for (int b = 0; b < NB; ++b) {
        s  += part[b * NC + c];
        s2 += part[NB * NC + b * NC + c];
    }
    const float inv_n = 1.f / (float)(NB * HWSZ);
    float mean = s * inv_n;
    float var  = s2 * inv_n - mean * mean;
    float scale = g[c] * rsqrtf(var + 1e-5f);
    sc[c] = scale;
    sc[NC + c] = bt[c] - mean * scale;
}

// ---------------------------------------------------------------------------
// Kernel 4: BN + leaky ReLU in place (layer 1)
// ---------------------------------------------------------------------------
__global__ __launch_bounds__(256) void bnlrelu_kernel(
    float* __restrict__ h, const float* __restrict__ sc)
{
    const int n4 = NB * NC * HWSZ / 4;
    for (int i = blockIdx.x * 256 + threadIdx.x; i < n4; i += gridDim.x * 256) {
        int c = (i >> 12) % NC;
        float scale = sc[c], shift = sc[NC + c];
        float4 v = ((const float4*)h)[i];
        float4 o;
        o.x = fmaf(scale, v.x, shift); o.x = o.x >= 0.f ? o.x : 0.1f * o.x;
        o.y = fmaf(scale, v.y, shift); o.y = o.y >= 0.f ? o.y : 0.1f * o.y;
        o.z = fmaf(scale, v.z, shift); o.z = o.z >= 0.f ? o.z : 0.1f * o.z;
        o.w = fmaf(scale, v.w, shift); o.w = o.w >= 0.f ? o.w : 0.1f * o.w;
        ((float4*)h)[i] = o;
    }
}

// ---------------------------------------------------------------------------
// Kernel 5: out = x + BN(out_raw) in place
// ---------------------------------------------------------------------------
__global__ __launch_bounds__(256) void final_kernel(
    float* __restrict__ out, const float* __restrict__ x,
    const float* __restrict__ sc)
{
    const int n4 = NB * NC * HWSZ / 4;
    for (int i = blockIdx.x * 256 + threadIdx.x; i < n4; i += gridDim.x * 256) {
        int c = (i >> 12) % NC;
        float scale = sc[c], shift = sc[NC + c];
        float4 v = ((const float4*)out)[i];
        float4 xv = ((const float4*)x)[i];
        float4 o;
        o.x = xv.x + fmaf(scale, v.x, shift);
        o.y = xv.y + fmaf(scale, v.y, shift);
        o.z = xv.z + fmaf(scale, v.z, shift);
        o.w = xv.w + fmaf(scale, v.w, shift);
        ((float4*)out)[i] = o;
    }
}

// ---------------------------------------------------------------------------
extern "C" void kernel_launch(void* const* d_in, const int* in_sizes, int n_in,
                              void* d_out, int out_size, void* d_ws, size_t ws_size,
                              hipStream_t stream)
{
    const float* x        = (const float*)d_in[0];
    const float* d1_off_w = (const float*)d_in[1];
    const float* d1_off_b = (const float*)d_in[2];
    const float* d1_mod_w = (const float*)d_in[3];
    const float* d1_mod_b = (const float*)d_in[4];
    const float* d1_w     = (const float*)d_in[5];
    const float* d2_off_w = (const float*)d_in[6];
    const float* d2_off_b = (const float*)d_in[7];
    const float* d2_mod_w = (const float*)d_in[8];
    const float* d2_mod_b = (const float*)d_in[9];
    const float* d2_w     = (const float*)d_in[10];
    const float* bn_g     = (const float*)d_in[11];
    const float* bn_b     = (const float*)d_in[12];
    float* out = (float*)d_out;

    // ws layout (floats): h1 | aux | wT | wd | sc | part
    float* h1   = (float*)d_ws;
    float* aux  = h1   + (size_t)NB * NC * HWSZ;      // 6291456
    float* wT   = aux  + (size_t)NB * AUXC * HWSZ;    // +1769472
    float* wd   = wT   + WT_ELEMS;                    // +24192
    float* sc   = wd   + WD_ELEMS;                    // +82944
    float* part = sc   + 2 * NC;                      // +192

    const int npix = NB * HWSZ;
    const int prep_blocks = (WT_ELEMS + WD_ELEMS + 255) / 256;

    // ---- layer 1 ----
    prep_weights_kernel<<<prep_blocks, 256, 0, stream>>>(d1_off_w, d1_mod_w, d1_w, wT, wd);
    conv27_kernel<<<NB * NH, 512, 0, stream>>>(x, wT, d1_off_b, d1_mod_b, aux);
    deform_kernel<<<npix / 64, 256, 0, stream>>>(x, aux, wd, h1);
    bnstats_kernel<<<NB * NC, 256, 0, stream>>>(h1, part);
    bnfinalize_kernel<<<1, 128, 0, stream>>>(part, bn_g, bn_b, sc);
    bnlrelu_kernel<<<2048, 256, 0, stream>>>(h1, sc);

    // ---- layer 2 ----
    prep_weights_kernel<<<prep_blocks, 256, 0, stream>>>(d2_off_w, d2_mod_w, d2_w, wT, wd);
    conv27_kernel<<<NB * NH, 512, 0, stream>>>(h1, wT, d2_off_b, d2_mod_b, aux);
    deform_kernel<<<npix / 64, 256, 0, stream>>>(h1, aux, wd, out);
    bnstats_kernel<<<NB * NC, 256, 0, stream>>>(out, part);
    bnfinalize_kernel<<<1, 128, 0, stream>>>(part, bn_g, bn_b, sc);
    final_kernel<<<2048, 256, 0, stream>>>(out, x, sc);
}

// Round 3
// 804.431 us; speedup vs baseline: 1.9636x; 1.7289x over previous
//
#include <hip/hip_runtime.h>
#include <math.h>

#define NB 4
#define NC 96
#define NH 128
#define NW 128
#define HWSZ (NH * NW)          // 16384
#define NK 9
#define AUXC 27                 // 18 offset + 9 mask channels
#define CKK (NC * NK)           // 864
#define WT_STRIDE 28            // 27 outputs + 1 pad
#define WT_ELEMS (CKK * WT_STRIDE)      // 24192
#define WD_ELEMS (CKK * NC)             // 82944

// ---------------------------------------------------------------------------
// Kernel 0: weight transposes for this layer.
//   wT[(c*9+tap)*28 + oc] = (oc<18 ? offw[oc][c][tap] : modw[oc-18][c][tap])
//   wd[(c*9+k)*96 + oc]   = w[oc][c][k]
// ---------------------------------------------------------------------------
__global__ __launch_bounds__(256) void prep_weights_kernel(
    const float* __restrict__ offw, const float* __restrict__ modw,
    const float* __restrict__ w,
    float* __restrict__ wT, float* __restrict__ wd)
{
    int idx = blockIdx.x * 256 + threadIdx.x;
    if (idx < WT_ELEMS) {
        int row = idx / WT_STRIDE;          // c*9+tap
        int col = idx - row * WT_STRIDE;    // oc
        float v = 0.f;
        if (col < 18)      v = offw[col * CKK + row];
        else if (col < 27) v = modw[(col - 18) * CKK + row];
        wT[idx] = v;
    }
    int j = idx - WT_ELEMS;
    if (j >= 0 && j < WD_ELEMS) {
        int row = j / NC;                   // c*9+k
        int oc  = j - row * NC;
        wd[j] = w[oc * CKK + row];
    }
}

// ---------------------------------------------------------------------------
// Kernel 1: 3x3 conv -> 18 offset + 9 mask (2*sigmoid applied).
// Block = 512 threads: px = t&127 (one row), g = t>>7 (4 channel groups of 24).
// Grid = NB*NH = 512 blocks.
// Spill-free: taps as named scalars, no pointer-passed arrays, no prefetch.
// ---------------------------------------------------------------------------
__global__ __launch_bounds__(512) void conv27_kernel(
    const float* __restrict__ in,
    const float* __restrict__ wT,
    const float* __restrict__ offb, const float* __restrict__ modb,
    float* __restrict__ aux)
{
    __shared__ float red[3][AUXC][NW];      // 41472 B

    int t  = threadIdx.x;
    int px = t & 127;
    int g  = t >> 7;
    int b  = blockIdx.x >> 7;
    int y  = blockIdx.x & 127;

    const bool hasT = (y > 0), hasB = (y < NH - 1);   // uniform
    const int offT = hasT ? NW : 0;        // clamped row offsets (stay in-bounds)
    const int offB = hasB ? NW : 0;
    int pxl = px > 0 ? px - 1 : 0;
    int pxr = px < NW - 1 ? px + 1 : NW - 1;
    const float mL = (px == 0) ? 0.f : 1.f;
    const float mR = (px == NW - 1) ? 0.f : 1.f;

    float acc[AUXC];
#pragma unroll
    for (int i = 0; i < AUXC; ++i) acc[i] = 0.f;

    const float* imgb = in + (size_t)b * NC * HWSZ + y * NW;
    int c0 = g * 24;

    for (int c = c0; c < c0 + 24; ++c) {
        const float* rm = imgb + c * HWSZ;
        const float* rt = rm - offT;
        const float* rb = rm + offB;
        float t0 = rt[pxl], t1 = rt[px], t2 = rt[pxr];
        float t3 = rm[pxl], t4 = rm[px], t5 = rm[pxr];
        float t6 = rb[pxl], t7 = rb[px], t8 = rb[pxr];
        if (!hasT) { t0 = 0.f; t1 = 0.f; t2 = 0.f; }   // uniform branch
        if (!hasB) { t6 = 0.f; t7 = 0.f; t8 = 0.f; }
        t0 *= mL; t3 *= mL; t6 *= mL;
        t2 *= mR; t5 *= mR; t8 *= mR;

        const float* wb = wT + c * NK * WT_STRIDE;     // uniform -> s_loads
#pragma unroll
        for (int oc = 0; oc < AUXC; ++oc) {
            float a = acc[oc];
            a = fmaf(t0, wb[0 * WT_STRIDE + oc], a);
            a = fmaf(t1, wb[1 * WT_STRIDE + oc], a);
            a = fmaf(t2, wb[2 * WT_STRIDE + oc], a);
            a = fmaf(t3, wb[3 * WT_STRIDE + oc], a);
            a = fmaf(t4, wb[4 * WT_STRIDE + oc], a);
            a = fmaf(t5, wb[5 * WT_STRIDE + oc], a);
            a = fmaf(t6, wb[6 * WT_STRIDE + oc], a);
            a = fmaf(t7, wb[7 * WT_STRIDE + oc], a);
            a = fmaf(t8, wb[8 * WT_STRIDE + oc], a);
            acc[oc] = a;
        }
    }

    if (g > 0) {
#pragma unroll
        for (int oc = 0; oc < AUXC; ++oc) red[g - 1][oc][px] = acc[oc];
    }
    __syncthreads();
    if (g == 0) {
        float* ap = aux + (size_t)b * AUXC * HWSZ + y * NW + px;
#pragma unroll
        for (int oc = 0; oc < AUXC; ++oc) {
            float s = acc[oc] + red[0][oc][px] + red[1][oc][px] + red[2][oc][px];
            if (oc < 18) {
                ap[oc * HWSZ] = s + offb[oc];
            } else {
                float z = s + modb[oc - 18];
                ap[oc * HWSZ] = 2.f / (1.f + __expf(-z));
            }
        }
    }
}

// ---------------------------------------------------------------------------
// Kernel 2: deformable sampling + contraction. (unchanged from round 2)
// ---------------------------------------------------------------------------
__global__ __launch_bounds__(256, 4) void deform_kernel(
    const float* __restrict__ in,    // (B,C,H,W)
    const float* __restrict__ aux,   // (B,27,H,W)
    const float* __restrict__ wd,    // [(c*9+k)*96 + oc]
    float* __restrict__ out)         // (B,C,H,W) pre-BN
{
    __shared__ int   sAddr[4][576];
    __shared__ float sWgt[4][576];
    __shared__ float sS[2][2][576];  // [buf][ch01][k*64+px]

    int t = threadIdx.x;
    int base = blockIdx.x * 64;
    int b = base >> 14;
    int rem0 = base & (HWSZ - 1);
    int y = rem0 >> 7;
    int x0 = rem0 & (NW - 1);

    const float* auxb = aux + (size_t)b * AUXC * HWSZ;

    // ---- geometry ----
    for (int e = t; e < 576; e += 256) {
        int px = e & 63;
        int k  = e >> 6;
        int xcol = x0 + px;
        int idx = y * NW + xcol;
        float offy = auxb[(2 * k) * HWSZ + idx];
        float offx = auxb[(2 * k + 1) * HWSZ + idx];
        float m    = auxb[(18 + k) * HWSZ + idx];
        int ky = k / 3, kx = k - 3 * (k / 3);
        float py  = (float)(y - 1 + ky) + offy;
        float pxf = (float)(xcol - 1 + kx) + offx;
        float y0f = floorf(py), x0f = floorf(pxf);
        float dy = py - y0f, dx = pxf - x0f;
        int iy0 = (int)y0f, ix0 = (int)x0f;
        int iy1 = iy0 + 1,  ix1 = ix0 + 1;

        bool vy0 = (iy0 >= 0) && (iy0 < NH);
        bool vy1 = (iy1 >= 0) && (iy1 < NH);
        bool vx0 = (ix0 >= 0) && (ix0 < NW);
        bool vx1 = (ix1 >= 0) && (ix1 < NW);
        int cy0 = min(max(iy0, 0), NH - 1);
        int cy1 = min(max(iy1, 0), NH - 1);
        int cx0 = min(max(ix0, 0), NW - 1);
        int cx1 = min(max(ix1, 0), NW - 1);

        float w00 = (1.f - dy) * (1.f - dx) * m; if (!(vy0 && vx0)) w00 = 0.f;
        float w01 = (1.f - dy) * dx * m;         if (!(vy0 && vx1)) w01 = 0.f;
        float w10 = dy * (1.f - dx) * m;         if (!(vy1 && vx0)) w10 = 0.f;
        float w11 = dy * dx * m;                 if (!(vy1 && vx1)) w11 = 0.f;

        sAddr[0][e] = cy0 * NW + cx0;  sWgt[0][e] = w00;
        sAddr[1][e] = cy0 * NW + cx1;  sWgt[1][e] = w01;
        sAddr[2][e] = cy1 * NW + cx0;  sWgt[2][e] = w10;
        sAddr[3][e] = cy1 * NW + cx1;  sWgt[3][e] = w11;
    }
    __syncthreads();

    float acc[24];
#pragma unroll
    for (int i = 0; i < 24; ++i) acc[i] = 0.f;

    int og = __builtin_amdgcn_readfirstlane(t >> 6);
    int px = t & 63;
    const float* xb = in + (size_t)b * NC * HWSZ;

    auto produce = [&](int c, int buf) {
        const float* xc0 = xb + c * HWSZ;
        const float* xc1 = xc0 + HWSZ;
#pragma unroll
        for (int r = 0; r < 3; ++r) {
            int e = t + r * 256;
            if (r < 2 || t < 64) {
                int   a0 = sAddr[0][e], a1 = sAddr[1][e];
                int   a2 = sAddr[2][e], a3 = sAddr[3][e];
                float w0 = sWgt[0][e], w1 = sWgt[1][e];
                float w2 = sWgt[2][e], w3 = sWgt[3][e];
                sS[buf][0][e] = w0 * xc0[a0] + w1 * xc0[a1]
                              + w2 * xc0[a2] + w3 * xc0[a3];
                sS[buf][1][e] = w0 * xc1[a0] + w1 * xc1[a1]
                              + w2 * xc1[a2] + w3 * xc1[a3];
            }
        }
    };

    produce(0, 0);
    __syncthreads();

    for (int c = 0; c < NC; c += 2) {
        int buf = (c >> 1) & 1;
        if (c + 2 < NC) produce(c + 2, buf ^ 1);

        float s0[NK], s1[NK];
#pragma unroll
        for (int k = 0; k < NK; ++k) {
            s0[k] = sS[buf][0][k * 64 + px];
            s1[k] = sS[buf][1][k * 64 + px];
        }
#pragma unroll
        for (int k = 0; k < NK; ++k) {
            const float* w0 = wd + (c * NK + k) * NC + og * 24;       // uniform
            const float* w1 = wd + ((c + 1) * NK + k) * NC + og * 24; // uniform
#pragma unroll
            for (int i = 0; i < 24; ++i) {
                acc[i] = fmaf(s0[k], w0[i], acc[i]);
                acc[i] = fmaf(s1[k], w1[i], acc[i]);
            }
        }
        __syncthreads();
    }

    int rem = y * NW + x0 + px;
    float* op = out + ((size_t)b * NC + og * 24) * HWSZ + rem;
#pragma unroll
    for (int i = 0; i < 24; ++i) op[i * HWSZ] = acc[i];
}

// ---------------------------------------------------------------------------
// Kernel 3a: per-(b,c) partial sums.  Kernel 3b: finalize scale/shift.
// ---------------------------------------------------------------------------
__global__ __launch_bounds__(256) void bnstats_kernel(
    const float* __restrict__ h, float* __restrict__ part)
{
    int bc = blockIdx.x;                 // 0..383 = b*NC+c
    const float4* p = (const float4*)(h + (size_t)bc * HWSZ);
    float s = 0.f, s2 = 0.f;
    for (int i = threadIdx.x; i < HWSZ / 4; i += 256) {
        float4 v = p[i];
        s  += v.x + v.y + v.z + v.w;
        s2 += v.x * v.x + v.y * v.y + v.z * v.z + v.w * v.w;
    }
#pragma unroll
    for (int o = 32; o > 0; o >>= 1) {
        s  += __shfl_down(s, o);
        s2 += __shfl_down(s2, o);
    }
    __shared__ float red[8];
    int wv = threadIdx.x >> 6, ln = threadIdx.x & 63;
    if (ln == 0) { red[wv] = s; red[4 + wv] = s2; }
    __syncthreads();
    if (threadIdx.x == 0) {
        part[bc]            = red[0] + red[1] + red[2] + red[3];
        part[NB * NC + bc]  = red[4] + red[5] + red[6] + red[7];
    }
}

__global__ __launch_bounds__(128) void bnfinalize_kernel(
    const float* __restrict__ part, const float* __restrict__ g,
    const float* __restrict__ bt, float* __restrict__ sc)
{
    int c = threadIdx.x;
    if (c >= NC) return;
    float s = 0.f, s2 = 0.f;
#pragma unroll
    for (int b = 0; b < NB; ++b) {
        s  += part[b * NC + c];
        s2 += part[NB * NC + b * NC + c];
    }
    const float inv_n = 1.f / (float)(NB * HWSZ);
    float mean = s * inv_n;
    float var  = s2 * inv_n - mean * mean;
    float scale = g[c] * rsqrtf(var + 1e-5f);
    sc[c] = scale;
    sc[NC + c] = bt[c] - mean * scale;
}

// ---------------------------------------------------------------------------
// Kernel 4: BN + leaky ReLU in place (layer 1)
// ---------------------------------------------------------------------------
__global__ __launch_bounds__(256) void bnlrelu_kernel(
    float* __restrict__ h, const float* __restrict__ sc)
{
    const int n4 = NB * NC * HWSZ / 4;
    for (int i = blockIdx.x * 256 + threadIdx.x; i < n4; i += gridDim.x * 256) {
        int c = (i >> 12) % NC;
        float scale = sc[c], shift = sc[NC + c];
        float4 v = ((const float4*)h)[i];
        float4 o;
        o.x = fmaf(scale, v.x, shift); o.x = o.x >= 0.f ? o.x : 0.1f * o.x;
        o.y = fmaf(scale, v.y, shift); o.y = o.y >= 0.f ? o.y : 0.1f * o.y;
        o.z = fmaf(scale, v.z, shift); o.z = o.z >= 0.f ? o.z : 0.1f * o.z;
        o.w = fmaf(scale, v.w, shift); o.w = o.w >= 0.f ? o.w : 0.1f * o.w;
        ((float4*)h)[i] = o;
    }
}

// ---------------------------------------------------------------------------
// Kernel 5: out = x + BN(out_raw) in place
// ---------------------------------------------------------------------------
__global__ __launch_bounds__(256) void final_kernel(
    float* __restrict__ out, const float* __restrict__ x,
    const float* __restrict__ sc)
{
    const int n4 = NB * NC * HWSZ / 4;
    for (int i = blockIdx.x * 256 + threadIdx.x; i < n4; i += gridDim.x * 256) {
        int c = (i >> 12) % NC;
        float scale = sc[c], shift = sc[NC + c];
        float4 v = ((const float4*)out)[i];
        float4 xv = ((const float4*)x)[i];
        float4 o;
        o.x = xv.x + fmaf(scale, v.x, shift);
        o.y = xv.y + fmaf(scale, v.y, shift);
        o.z = xv.z + fmaf(scale, v.z, shift);
        o.w = xv.w + fmaf(scale, v.w, shift);
        ((float4*)out)[i] = o;
    }
}

// ---------------------------------------------------------------------------
extern "C" void kernel_launch(void* const* d_in, const int* in_sizes, int n_in,
                              void* d_out, int out_size, void* d_ws, size_t ws_size,
                              hipStream_t stream)
{
    const float* x        = (const float*)d_in[0];
    const float* d1_off_w = (const float*)d_in[1];
    const float* d1_off_b = (const float*)d_in[2];
    const float* d1_mod_w = (const float*)d_in[3];
    const float* d1_mod_b = (const float*)d_in[4];
    const float* d1_w     = (const float*)d_in[5];
    const float* d2_off_w = (const float*)d_in[6];
    const float* d2_off_b = (const float*)d_in[7];
    const float* d2_mod_w = (const float*)d_in[8];
    const float* d2_mod_b = (const float*)d_in[9];
    const float* d2_w     = (const float*)d_in[10];
    const float* bn_g     = (const float*)d_in[11];
    const float* bn_b     = (const float*)d_in[12];
    float* out = (float*)d_out;

    // ws layout (floats): h1 | aux | wT | wd | sc | part
    float* h1   = (float*)d_ws;
    float* aux  = h1   + (size_t)NB * NC * HWSZ;      // 6291456
    float* wT   = aux  + (size_t)NB * AUXC * HWSZ;    // +1769472
    float* wd   = wT   + WT_ELEMS;                    // +24192
    float* sc   = wd   + WD_ELEMS;                    // +82944
    float* part = sc   + 2 * NC;                      // +192

    const int npix = NB * HWSZ;
    const int prep_blocks = (WT_ELEMS + WD_ELEMS + 255) / 256;

    // ---- layer 1 ----
    prep_weights_kernel<<<prep_blocks, 256, 0, stream>>>(d1_off_w, d1_mod_w, d1_w, wT, wd);
    conv27_kernel<<<NB * NH, 512, 0, stream>>>(x, wT, d1_off_b, d1_mod_b, aux);
    deform_kernel<<<npix / 64, 256, 0, stream>>>(x, aux, wd, h1);
    bnstats_kernel<<<NB * NC, 256, 0, stream>>>(h1, part);
    bnfinalize_kernel<<<1, 128, 0, stream>>>(part, bn_g, bn_b, sc);
    bnlrelu_kernel<<<2048, 256, 0, stream>>>(h1, sc);

    // ---- layer 2 ----
    prep_weights_kernel<<<prep_blocks, 256, 0, stream>>>(d2_off_w, d2_mod_w, d2_w, wT, wd);
    conv27_kernel<<<NB * NH, 512, 0, stream>>>(h1, wT, d2_off_b, d2_mod_b, aux);
    deform_kernel<<<npix / 64, 256, 0, stream>>>(h1, aux, wd, out);
    bnstats_kernel<<<NB * NC, 256, 0, stream>>>(out, part);
    bnfinalize_kernel<<<1, 128, 0, stream>>>(part, bn_g, bn_b, sc);
    final_kernel<<<2048, 256, 0, stream>>>(out, x, sc);
}

// Round 4
// 788.193 us; speedup vs baseline: 2.0041x; 1.0206x over previous
//
#include <hip/hip_runtime.h>
#include <math.h>

#define NB 4
#define NC 96
#define NH 128
#define NW 128
#define HWSZ (NH * NW)          // 16384
#define NK 9
#define AUXC 27                 // 18 offset + 9 mask channels
#define CKK (NC * NK)           // 864
#define WT_STRIDE 28            // 27 outputs + 1 pad
#define WT_ELEMS (CKK * WT_STRIDE)      // 24192
#define WB_ELEMS (NC * CKK)             // 82944 bf16 deform weights

typedef __attribute__((ext_vector_type(8))) short bf16x8;
typedef __attribute__((ext_vector_type(4))) float f32x4;

__device__ __forceinline__ unsigned int bf16r(float f) {
    unsigned int u = __float_as_uint(f);
    u += 0x7fffu + ((u >> 16) & 1u);
    return u >> 16;                      // RNE bf16 bits
}

// ---------------------------------------------------------------------------
// Kernel 0: weight prep.
//   wT[(c*9+tap)*28 + oc]  (fp32, conv27)
//   wb16[oc*864 + c*9 + k] (bf16 bits, deform MFMA A) -- same index order as w
// ---------------------------------------------------------------------------
__global__ __launch_bounds__(256) void prep_weights_kernel(
    const float* __restrict__ offw, const float* __restrict__ modw,
    const float* __restrict__ w,
    float* __restrict__ wT, unsigned short* __restrict__ wb16)
{
    int idx = blockIdx.x * 256 + threadIdx.x;
    if (idx < WT_ELEMS) {
        int row = idx / WT_STRIDE;          // c*9+tap
        int col = idx - row * WT_STRIDE;    // oc
        float v = 0.f;
        if (col < 18)      v = offw[col * CKK + row];
        else if (col < 27) v = modw[(col - 18) * CKK + row];
        wT[idx] = v;
    }
    int j = idx - WT_ELEMS;
    if (j >= 0 && j < WB_ELEMS) {
        wb16[j] = (unsigned short)bf16r(w[j]);
    }
}

// ---------------------------------------------------------------------------
// Kernel 1: 3x3 conv -> 18 offset + 9 mask (2*sigmoid). (unchanged, fp32)
// ---------------------------------------------------------------------------
__global__ __launch_bounds__(512) void conv27_kernel(
    const float* __restrict__ in,
    const float* __restrict__ wT,
    const float* __restrict__ offb, const float* __restrict__ modb,
    float* __restrict__ aux)
{
    __shared__ float red[3][AUXC][NW];      // 41472 B

    int t  = threadIdx.x;
    int px = t & 127;
    int g  = t >> 7;
    int b  = blockIdx.x >> 7;
    int y  = blockIdx.x & 127;

    const bool hasT = (y > 0), hasB = (y < NH - 1);   // uniform
    const int offT = hasT ? NW : 0;
    const int offB = hasB ? NW : 0;
    int pxl = px > 0 ? px - 1 : 0;
    int pxr = px < NW - 1 ? px + 1 : NW - 1;
    const float mL = (px == 0) ? 0.f : 1.f;
    const float mR = (px == NW - 1) ? 0.f : 1.f;

    float acc[AUXC];
#pragma unroll
    for (int i = 0; i < AUXC; ++i) acc[i] = 0.f;

    const float* imgb = in + (size_t)b * NC * HWSZ + y * NW;
    int c0 = g * 24;

    for (int c = c0; c < c0 + 24; ++c) {
        const float* rm = imgb + c * HWSZ;
        const float* rt = rm - offT;
        const float* rb = rm + offB;
        float t0 = rt[pxl], t1 = rt[px], t2 = rt[pxr];
        float t3 = rm[pxl], t4 = rm[px], t5 = rm[pxr];
        float t6 = rb[pxl], t7 = rb[px], t8 = rb[pxr];
        if (!hasT) { t0 = 0.f; t1 = 0.f; t2 = 0.f; }
        if (!hasB) { t6 = 0.f; t7 = 0.f; t8 = 0.f; }
        t0 *= mL; t3 *= mL; t6 *= mL;
        t2 *= mR; t5 *= mR; t8 *= mR;

        const float* wb = wT + c * NK * WT_STRIDE;     // uniform -> s_loads
#pragma unroll
        for (int oc = 0; oc < AUXC; ++oc) {
            float a = acc[oc];
            a = fmaf(t0, wb[0 * WT_STRIDE + oc], a);
            a = fmaf(t1, wb[1 * WT_STRIDE + oc], a);
            a = fmaf(t2, wb[2 * WT_STRIDE + oc], a);
            a = fmaf(t3, wb[3 * WT_STRIDE + oc], a);
            a = fmaf(t4, wb[4 * WT_STRIDE + oc], a);
            a = fmaf(t5, wb[5 * WT_STRIDE + oc], a);
            a = fmaf(t6, wb[6 * WT_STRIDE + oc], a);
            a = fmaf(t7, wb[7 * WT_STRIDE + oc], a);
            a = fmaf(t8, wb[8 * WT_STRIDE + oc], a);
            acc[oc] = a;
        }
    }

    if (g > 0) {
#pragma unroll
        for (int oc = 0; oc < AUXC; ++oc) red[g - 1][oc][px] = acc[oc];
    }
    __syncthreads();
    if (g == 0) {
        float* ap = aux + (size_t)b * AUXC * HWSZ + y * NW + px;
#pragma unroll
        for (int oc = 0; oc < AUXC; ++oc) {
            float s = acc[oc] + red[0][oc][px] + red[1][oc][px] + red[2][oc][px];
            if (oc < 18) {
                ap[oc * HWSZ] = s + offb[oc];
            } else {
                float z = s + modb[oc - 18];
                ap[oc * HWSZ] = 2.f / (1.f + __expf(-z));
            }
        }
    }
}

// ---------------------------------------------------------------------------
// Kernel 2: deformable sampling + MFMA contraction.
// Block = 64 px (half row) x 96 oc; 256 threads = 4 waves.
// Wave wv owns px n-tile [wv*16, wv*16+16) and all 6 oc m-tiles.
// Geometry in LDS (uint4 per (k,px): 4 u16 byte-offsets + 4 bf16 weights);
// B-fragment samples computed per-lane in registers (each (ck,px) sample is
// needed by exactly one lane). No barriers in the K-loop.
// MFMA 16x16x32 bf16: A[m=l&15][k=(l>>4)*8+j], B[k][n=l&15],
// D col=l&15, row=(l>>4)*4+reg (m89-verified).
// ---------------------------------------------------------------------------
__global__ __launch_bounds__(256) void deform_mfma_kernel(
    const float* __restrict__ in,              // (B,C,H,W) fp32
    const float* __restrict__ aux,             // (B,27,H,W)
    const unsigned short* __restrict__ wb16,   // [oc][ck] bf16
    float* __restrict__ out)                   // (B,C,H,W) pre-BN
{
    __shared__ uint4 sGeo[NK][65];             // padded row -> uniform banks

    int t = threadIdx.x;
    int base = blockIdx.x * 64;
    int b = base >> 14;
    int rem0 = base & (HWSZ - 1);
    int y = rem0 >> 7;
    int x0 = rem0 & (NW - 1);                  // 0 or 64

    const float* auxb = aux + (size_t)b * AUXC * HWSZ;

    // ---- geometry: per (k, px): 4 clamped taps + mask-folded weights ----
    for (int e = t; e < 576; e += 256) {
        int px = e & 63;
        int k  = e >> 6;
        int xcol = x0 + px;
        int idx = y * NW + xcol;
        float offy = auxb[(2 * k) * HWSZ + idx];
        float offx = auxb[(2 * k + 1) * HWSZ + idx];
        float m    = auxb[(18 + k) * HWSZ + idx];
        int ky = k / 3, kx = k - 3 * (k / 3);
        float py  = (float)(y - 1 + ky) + offy;
        float pxf = (float)(xcol - 1 + kx) + offx;
        float y0f = floorf(py), x0f = floorf(pxf);
        float dy = py - y0f, dx = pxf - x0f;
        int iy0 = (int)y0f, ix0 = (int)x0f;
        int iy1 = iy0 + 1,  ix1 = ix0 + 1;

        bool vy0 = (iy0 >= 0) && (iy0 < NH);
        bool vy1 = (iy1 >= 0) && (iy1 < NH);
        bool vx0 = (ix0 >= 0) && (ix0 < NW);
        bool vx1 = (ix1 >= 0) && (ix1 < NW);
        int cy0 = min(max(iy0, 0), NH - 1);
        int cy1 = min(max(iy1, 0), NH - 1);
        int cx0 = min(max(ix0, 0), NW - 1);
        int cx1 = min(max(ix1, 0), NW - 1);

        float g00 = (1.f - dy) * (1.f - dx) * m; if (!(vy0 && vx0)) g00 = 0.f;
        float g01 = (1.f - dy) * dx * m;         if (!(vy0 && vx1)) g01 = 0.f;
        float g10 = dy * (1.f - dx) * m;         if (!(vy1 && vx0)) g10 = 0.f;
        float g11 = dy * dx * m;                 if (!(vy1 && vx1)) g11 = 0.f;

        unsigned int a0 = (unsigned int)((cy0 * NW + cx0) * 4);  // byte offs
        unsigned int a1 = (unsigned int)((cy0 * NW + cx1) * 4);
        unsigned int a2 = (unsigned int)((cy1 * NW + cx0) * 4);
        unsigned int a3 = (unsigned int)((cy1 * NW + cx1) * 4);

        uint4 gg;
        gg.x = a0 | (a1 << 16);
        gg.y = a2 | (a3 << 16);
        gg.z = bf16r(g00) | (bf16r(g01) << 16);
        gg.w = bf16r(g10) | (bf16r(g11) << 16);
        sGeo[k][px] = gg;
    }
    __syncthreads();

    f32x4 acc[6];
#pragma unroll
    for (int i = 0; i < 6; ++i) acc[i] = (f32x4){0.f, 0.f, 0.f, 0.f};

    const int lane15   = t & 15;
    const int g        = (t >> 4) & 3;         // k-group within wave
    const int wv       = t >> 6;               // wave id = n-tile
    const int px_local = (wv << 4) | lane15;

    const char* xcb = (const char*)in + ((size_t)b * NC * HWSZ * 4);

    for (int k0 = 0; k0 < CKK; k0 += 32) {
        // A fragments: 6 m-tiles, 16B each, L2-resident
        bf16x8 afr[6];
#pragma unroll
        for (int i = 0; i < 6; ++i)
            afr[i] = *(const bf16x8*)(wb16 + (i * 16 + lane15) * CKK + k0 + g * 8);

        // B fragment: 8 samples computed in-register
        bf16x8 bfr;
        int kkb = k0 + g * 8;
#pragma unroll
        for (int j = 0; j < 8; ++j) {
            int kk = kkb + j;
            int c  = kk / 9;
            int k  = kk - c * 9;
            uint4 geo = sGeo[k][px_local];
            const char* p = xcb + ((size_t)c << 16);   // c*HWSZ*4 bytes
            float v0 = *(const float*)(p + (geo.x & 0xffffu));
            float v1 = *(const float*)(p + (geo.x >> 16));
            float v2 = *(const float*)(p + (geo.y & 0xffffu));
            float v3 = *(const float*)(p + (geo.y >> 16));
            float w0 = __uint_as_float(geo.z << 16);
            float w1 = __uint_as_float(geo.z & 0xffff0000u);
            float w2 = __uint_as_float(geo.w << 16);
            float w3 = __uint_as_float(geo.w & 0xffff0000u);
            float s = v0 * w0;
            s = fmaf(v1, w1, s);
            s = fmaf(v2, w2, s);
            s = fmaf(v3, w3, s);
            bfr[j] = (short)bf16r(s);
        }

#pragma unroll
        for (int i = 0; i < 6; ++i)
            acc[i] = __builtin_amdgcn_mfma_f32_16x16x32_bf16(afr[i], bfr, acc[i], 0, 0, 0);
    }

    float* ob = out + (size_t)b * NC * HWSZ + y * NW + x0 + px_local;
#pragma unroll
    for (int i = 0; i < 6; ++i) {
        int row0 = i * 16 + g * 4;
#pragma unroll
        for (int r = 0; r < 4; ++r)
            ob[(row0 + r) * HWSZ] = acc[i][r];
    }
}

// ---------------------------------------------------------------------------
// Kernel 3a: per-(b,c) partial sums.  Kernel 3b: finalize scale/shift.
// ---------------------------------------------------------------------------
__global__ __launch_bounds__(256) void bnstats_kernel(
    const float* __restrict__ h, float* __restrict__ part)
{
    int bc = blockIdx.x;                 // 0..383 = b*NC+c
    const float4* p = (const float4*)(h + (size_t)bc * HWSZ);
    float s = 0.f, s2 = 0.f;
    for (int i = threadIdx.x; i < HWSZ / 4; i += 256) {
        float4 v = p[i];
        s  += v.x + v.y + v.z + v.w;
        s2 += v.x * v.x + v.y * v.y + v.z * v.z + v.w * v.w;
    }
#pragma unroll
    for (int o = 32; o > 0; o >>= 1) {
        s  += __shfl_down(s, o);
        s2 += __shfl_down(s2, o);
    }
    __shared__ float red[8];
    int wv = threadIdx.x >> 6, ln = threadIdx.x & 63;
    if (ln == 0) { red[wv] = s; red[4 + wv] = s2; }
    __syncthreads();
    if (threadIdx.x == 0) {
        part[bc]            = red[0] + red[1] + red[2] + red[3];
        part[NB * NC + bc]  = red[4] + red[5] + red[6] + red[7];
    }
}

__global__ __launch_bounds__(128) void bnfinalize_kernel(
    const float* __restrict__ part, const float* __restrict__ g,
    const float* __restrict__ bt, float* __restrict__ sc)
{
    int c = threadIdx.x;
    if (c >= NC) return;
    float s = 0.f, s2 = 0.f;
#pragma unroll
    for (int b = 0; b < NB; ++b) {
        s  += part[b * NC + c];
        s2 += part[NB * NC + b * NC + c];
    }
    const float inv_n = 1.f / (float)(NB * HWSZ);
    float mean = s * inv_n;
    float var  = s2 * inv_n - mean * mean;
    float scale = g[c] * rsqrtf(var + 1e-5f);
    sc[c] = scale;
    sc[NC + c] = bt[c] - mean * scale;
}

// ---------------------------------------------------------------------------
// Kernel 4: BN + leaky ReLU in place (layer 1)
// ---------------------------------------------------------------------------
__global__ __launch_bounds__(256) void bnlrelu_kernel(
    float* __restrict__ h, const float* __restrict__ sc)
{
    const int n4 = NB * NC * HWSZ / 4;
    for (int i = blockIdx.x * 256 + threadIdx.x; i < n4; i += gridDim.x * 256) {
        int c = (i >> 12) % NC;
        float scale = sc[c], shift = sc[NC + c];
        float4 v = ((const float4*)h)[i];
        float4 o;
        o.x = fmaf(scale, v.x, shift); o.x = o.x >= 0.f ? o.x : 0.1f * o.x;
        o.y = fmaf(scale, v.y, shift); o.y = o.y >= 0.f ? o.y : 0.1f * o.y;
        o.z = fmaf(scale, v.z, shift); o.z = o.z >= 0.f ? o.z : 0.1f * o.z;
        o.w = fmaf(scale, v.w, shift); o.w = o.w >= 0.f ? o.w : 0.1f * o.w;
        ((float4*)h)[i] = o;
    }
}

// ---------------------------------------------------------------------------
// Kernel 5: out = x + BN(out_raw) in place
// ---------------------------------------------------------------------------
__global__ __launch_bounds__(256) void final_kernel(
    float* __restrict__ out, const float* __restrict__ x,
    const float* __restrict__ sc)
{
    const int n4 = NB * NC * HWSZ / 4;
    for (int i = blockIdx.x * 256 + threadIdx.x; i < n4; i += gridDim.x * 256) {
        int c = (i >> 12) % NC;
        float scale = sc[c], shift = sc[NC + c];
        float4 v = ((const float4*)out)[i];
        float4 xv = ((const float4*)x)[i];
        float4 o;
        o.x = xv.x + fmaf(scale, v.x, shift);
        o.y = xv.y + fmaf(scale, v.y, shift);
        o.z = xv.z + fmaf(scale, v.z, shift);
        o.w = xv.w + fmaf(scale, v.w, shift);
        ((float4*)out)[i] = o;
    }
}

// ---------------------------------------------------------------------------
extern "C" void kernel_launch(void* const* d_in, const int* in_sizes, int n_in,
                              void* d_out, int out_size, void* d_ws, size_t ws_size,
                              hipStream_t stream)
{
    const float* x        = (const float*)d_in[0];
    const float* d1_off_w = (const float*)d_in[1];
    const float* d1_off_b = (const float*)d_in[2];
    const float* d1_mod_w = (const float*)d_in[3];
    const float* d1_mod_b = (const float*)d_in[4];
    const float* d1_w     = (const float*)d_in[5];
    const float* d2_off_w = (const float*)d_in[6];
    const float* d2_off_b = (const float*)d_in[7];
    const float* d2_mod_w = (const float*)d_in[8];
    const float* d2_mod_b = (const float*)d_in[9];
    const float* d2_w     = (const float*)d_in[10];
    const float* bn_g     = (const float*)d_in[11];
    const float* bn_b     = (const float*)d_in[12];
    float* out = (float*)d_out;

    // ws layout (floats): h1 | aux | wT | wb16(41472 f worth) | sc | part
    float* h1   = (float*)d_ws;
    float* aux  = h1   + (size_t)NB * NC * HWSZ;      // 6291456
    float* wT   = aux  + (size_t)NB * AUXC * HWSZ;    // +1769472
    unsigned short* wb16 = (unsigned short*)(wT + WT_ELEMS);
    float* sc   = wT + WT_ELEMS + WB_ELEMS / 2;       // wb16 = 82944 u16
    float* part = sc + 2 * NC;

    const int npix = NB * HWSZ;                       // 65536
    const int prep_blocks = (WT_ELEMS + WB_ELEMS + 255) / 256;

    // ---- layer 1 ----
    prep_weights_kernel<<<prep_blocks, 256, 0, stream>>>(d1_off_w, d1_mod_w, d1_w, wT, wb16);
    conv27_kernel<<<NB * NH, 512, 0, stream>>>(x, wT, d1_off_b, d1_mod_b, aux);
    deform_mfma_kernel<<<npix / 64, 256, 0, stream>>>(x, aux, wb16, h1);
    bnstats_kernel<<<NB * NC, 256, 0, stream>>>(h1, part);
    bnfinalize_kernel<<<1, 128, 0, stream>>>(part, bn_g, bn_b, sc);
    bnlrelu_kernel<<<2048, 256, 0, stream>>>(h1, sc);

    // ---- layer 2 ----
    prep_weights_kernel<<<prep_blocks, 256, 0, stream>>>(d2_off_w, d2_mod_w, d2_w, wT, wb16);
    conv27_kernel<<<NB * NH, 512, 0, stream>>>(h1, wT, d2_off_b, d2_mod_b, aux);
    deform_mfma_kernel<<<npix / 64, 256, 0, stream>>>(h1, aux, wb16, out);
    bnstats_kernel<<<NB * NC, 256, 0, stream>>>(out, part);
    bnfinalize_kernel<<<1, 128, 0, stream>>>(part, bn_g, bn_b, sc);
    final_kernel<<<2048, 256, 0, stream>>>(out, x, sc);
}